// Round 5
// baseline (84.904 us; speedup 1.0000x reference)
//
#include <hip/hip_runtime.h>

#define Lc     1024
#define Cc     256
#define WINc   80
#define SLOTS  96      // padded slot/K dimension (6 MFMA K-steps of 16)
#define RS     104     // winb row stride in bf16 elems (208 B, 16B-aligned)
#define GSTRIDE 96     // Gt row stride (bf16 elems), 192 B
#define L2E    1.44269504088896340736f

typedef __attribute__((ext_vector_type(8)))  short bf16x8;
typedef __attribute__((ext_vector_type(16))) float f32x16;
typedef __attribute__((ext_vector_type(4)))  unsigned int u32x4;

__device__ inline float bf2f(unsigned short h) { return __uint_as_float(((unsigned int)h) << 16); }
__device__ inline unsigned int cvt_pk_bf16(float lo, float hi) {
    unsigned int r;
    asm("v_cvt_pk_bf16_f32 %0, %1, %2" : "=v"(r) : "v"(lo), "v"(hi));
    return r;
}
__device__ inline unsigned short f2bf(float f) {
    unsigned int u = __float_as_uint(f);
    unsigned int r = u + 0x7FFFu + ((u >> 16) & 1u);
    return (unsigned short)(r >> 16);
}

// ---------------------------------------------------------------------------
// Precompute into d_ws:
//  Gt[delta][s][i] (2 x 96 x 96 bf16, x log2e): physical slot s holds logical
//  T-column j = swap23(s):
//    j in [delta, delta+80): G_delta[i][j] = G[i-delta][j-delta]
//                            = sum_f Wq[i-delta,f] * Wk[j-delta,f]
//    j == 81              : b2_delta[i] = sum_f bq[f] * Wk[(i-delta),f]
//    else 0.   (i outside [delta, delta+80) -> 0)
//  swap23 makes step1's 32x32 MFMA C-layout == step2's A-fragment layout.
//  WvWf[w][co] = (1/256) * sum_f Wv[w,f]*Wf[f,co];  bias3 = bv@Wf + bf.
//  bk is provably unused (row-constant in softmax).
// ---------------------------------------------------------------------------
__global__ __launch_bounds__(256) void precompute_kernel(
    const float* __restrict__ Wq, const float* __restrict__ bq,
    const float* __restrict__ Wk, const float* __restrict__ Wv,
    const float* __restrict__ bv, const float* __restrict__ Wf,
    const float* __restrict__ bf,
    unsigned short* __restrict__ Gt, float* __restrict__ WvWf,
    float* __restrict__ bias3)
{
    const int b = blockIdx.x;
    const int t = threadIdx.x;
    if (b < 2 * SLOTS) {
        if (t >= SLOTS) return;
        const int dl = b / SLOTS;
        const int s  = b % SLOTS;
        const int j  = (s & ~12) | ((s & 4) << 1) | ((s & 8) >> 1); // swap bits 2,3
        const int i  = t;
        float acc = 0.f;
        bool nz = false;
        if (j == 81) {
            if (i >= dl && i - dl < WINc) {
                nz = true;
                for (int f = 0; f < 256; ++f)
                    acc = fmaf(bq[f], Wk[(i - dl) * 256 + f], acc);
            }
        } else if (j < 81 && j >= dl && j - dl < WINc && i >= dl && i - dl < WINc) {
            nz = true;
            for (int f = 0; f < 256; ++f)
                acc = fmaf(Wq[(i - dl) * 256 + f], Wk[(j - dl) * 256 + f], acc);
        }
        Gt[dl * SLOTS * GSTRIDE + s * GSTRIDE + i] = nz ? f2bf(acc * L2E) : (unsigned short)0;
    } else if (b < 2 * SLOTS + WINc) {
        const int w = b - 2 * SLOTS;
        float acc = 0.f;
        for (int f = 0; f < 256; ++f)
            acc = fmaf(Wv[w * 256 + f], Wf[f * 256 + t], acc);
        WvWf[w * 256 + t] = acc * (1.0f / 256.0f);
    } else {
        float acc = bf[t];
        for (int f = 0; f < 256; ++f)
            acc = fmaf(bv[f], Wf[f * 256 + t], acc);
        bias3[t] = acc;
    }
}

// ---------------------------------------------------------------------------
// step1 (tt = Gt' @ win^T) + beta extract + A-fragment pack for step2
// ---------------------------------------------------------------------------
__device__ inline void make_af(const unsigned short* __restrict__ Gtab,
                               const bf16x8 bwin[6], float* sbeta_buf,
                               bf16x8 af[6], int wid, int ln31, int hh)
{
    f32x16 tt[3];
    #pragma unroll
    for (int mt = 0; mt < 3; ++mt) {
        f32x16 a;
        #pragma unroll
        for (int r = 0; r < 16; ++r) a[r] = 0.f;
        #pragma unroll
        for (int t = 0; t < 6; ++t) {
            bf16x8 g = *(const bf16x8*)&Gtab[(mt * 32 + ln31) * GSTRIDE + t * 16 + hh * 8];
            a = __builtin_amdgcn_mfma_f32_32x32x16_bf16(g, bwin[t], a, 0, 0, 0);
        }
        tt[mt] = a;
    }
    // logical slot 81 (= physical 81 = tt[2][9], hh==0) is beta for this sub
    if (hh == 0) sbeta_buf[wid * 32 + ln31] = tt[2][9];
    #pragma unroll
    for (int t = 0; t < 6; ++t) {
        const int m = t >> 1, o = 8 * (t & 1);
        union { u32x4 u; bf16x8 v; } pk;
        pk.u.x = cvt_pk_bf16(tt[m][o + 0], tt[m][o + 1]);
        pk.u.y = cvt_pk_bf16(tt[m][o + 2], tt[m][o + 3]);
        pk.u.z = cvt_pk_bf16(tt[m][o + 4], tt[m][o + 5]);
        pk.u.w = cvt_pk_bf16(tt[m][o + 6], tt[m][o + 7]);
        af[t] = pk.v;
    }
}

// softmax (no max-subtract; log2e prebaked) + per-wave column partials
__device__ inline void softmax_colpart(f32x16 acc[8], const float* sbeta_buf,
                                       float* colpart, int wid, int lane)
{
    const int ln31 = lane & 31;
    float zp[16];
    #pragma unroll
    for (int r = 0; r < 16; ++r) zp[r] = 0.f;
    #pragma unroll
    for (int nt = 0; nt < 8; ++nt) {
        const float sb = sbeta_buf[nt * 32 + ln31];
        #pragma unroll
        for (int r = 0; r < 16; ++r) {
            const float e = exp2f(acc[nt][r] + sb);
            acc[nt][r] = e;
            zp[r] += e;
        }
    }
    #pragma unroll
    for (int r = 0; r < 16; ++r) {
        float z = zp[r];
        z += __shfl_xor(z, 1);
        z += __shfl_xor(z, 2);
        z += __shfl_xor(z, 4);
        z += __shfl_xor(z, 8);
        z += __shfl_xor(z, 16);
        zp[r] = __builtin_amdgcn_rcpf(z);
    }
    #pragma unroll
    for (int nt = 0; nt < 8; ++nt) {
        float v = 0.f;
        #pragma unroll
        for (int r = 0; r < 16; ++r) v = fmaf(acc[nt][r], zp[r], v);
        v += __shfl_xor(v, 32);
        if (lane < 32) colpart[wid * Cc + nt * 32 + ln31] = v;
    }
}

// ---------------------------------------------------------------------------
// Main kernel: one block (512 thr = 8 waves) per PAIR of positions (2b, 2b+1).
// Shared 81-col window; shift folded into precomputed Gt tables (delta 0/1).
// ---------------------------------------------------------------------------
__global__ __launch_bounds__(512, 2) void local_attn_kernel(
    const float* __restrict__ x,
    const unsigned short* __restrict__ Gt,
    const float* __restrict__ WvWf, const float* __restrict__ bias3,
    float* __restrict__ out)
{
    __shared__ __align__(16) unsigned short winb[Cc * RS];  // 53248 B
    __shared__ float sbeta0[Cc], sbeta1[Cc];                 // 2 KB
    __shared__ float colpart[8 * Cc];                        // 8 KB
    __shared__ float sbarAcc[Cc];                            // 1 KB
    __shared__ float upart[4 * WINc];                        // 1.25 KB
    __shared__ float ubuf[WINc];
    __shared__ float outpart[2 * Cc];                        // 2 KB

    const int bid = blockIdx.x;
    const int lA = 2 * bid, lB = lA + 1;
    int sA = lA - WINc / 2; sA = sA < 0 ? 0 : (sA > (Lc - WINc) ? (Lc - WINc) : sA);
    int sB = lB - WINc / 2; sB = sB < 0 ? 0 : (sB > (Lc - WINc) ? (Lc - WINc) : sB);
    const int dB = sB - sA;   // 0 or 1

    const int tid  = threadIdx.x;
    const int lane = tid & 63;
    const int wid  = tid >> 6;     // 0..7
    const int ln31 = lane & 31;
    const int hh   = lane >> 5;    // 0/1

    // ---- P0: stage 81-col window (cols 81..95 zeroed) ----
    for (int i = tid; i < Cc * 12; i += 512) {
        const int c  = i / 12;
        const int ch = i - c * 12;
        union { u32x4 u; bf16x8 v; } pk;
        if (ch < 10) {
            const float* xp = &x[c * Lc + sA + ch * 8];
            pk.u.x = cvt_pk_bf16(xp[0], xp[1]);
            pk.u.y = cvt_pk_bf16(xp[2], xp[3]);
            pk.u.z = cvt_pk_bf16(xp[4], xp[5]);
            pk.u.w = cvt_pk_bf16(xp[6], xp[7]);
        } else if (ch == 10) {
            const float v0 = (sA + 80 < Lc) ? x[c * Lc + sA + 80] : 0.f;
            pk.u.x = cvt_pk_bf16(v0, 0.f);
            pk.u.y = 0u; pk.u.z = 0u; pk.u.w = 0u;
        } else {
            pk.u.x = 0u; pk.u.y = 0u; pk.u.z = 0u; pk.u.w = 0u;
        }
        *(u32x4*)&winb[c * RS + ch * 8] = pk.u;
    }
    __syncthreads();

    // ---- P1: step1 for both subs (Gt from global/L2) + merged step2 ----
    bf16x8 bwin[6];
    #pragma unroll
    for (int t = 0; t < 6; ++t)
        bwin[t] = *(const bf16x8*)&winb[(wid * 32 + ln31) * RS + t * 16 + hh * 8];

    bf16x8 afA[6], afB[6];
    make_af(Gt, bwin, sbeta0, afA, wid, ln31, hh);
    make_af(Gt + dB * SLOTS * GSTRIDE, bwin, sbeta1, afB, wid, ln31, hh);

    f32x16 accA[8], accB[8];
    #pragma unroll
    for (int nt = 0; nt < 8; ++nt) {
        f32x16 a, b;
        #pragma unroll
        for (int r = 0; r < 16; ++r) { a[r] = 0.f; b[r] = 0.f; }
        #pragma unroll
        for (int t = 0; t < 6; ++t) {
            bf16x8 bb = *(const bf16x8*)&winb[(nt * 32 + ln31) * RS + t * 16 + hh * 8];
            a = __builtin_amdgcn_mfma_f32_32x32x16_bf16(afA[t], bb, a, 0, 0, 0);
            b = __builtin_amdgcn_mfma_f32_32x32x16_bf16(afB[t], bb, b, 0, 0, 0);
        }
        accA[nt] = a; accB[nt] = b;
    }
    __syncthreads();

    // ---- P2: softmax_a + column partials ----
    softmax_colpart(accA, sbeta0, colpart, wid, lane);
    __syncthreads();

    // ---- P3: sbar_a ----
    if (tid < Cc) {
        float v = 0.f;
        #pragma unroll
        for (int w8 = 0; w8 < 8; ++w8) v += colpart[w8 * Cc + tid];
        sbarAcc[tid] = v;
    }
    __syncthreads();

    // ---- P4: softmax_b + colpart_b ; u_a ----
    softmax_colpart(accB, sbeta1, colpart, wid, lane);
    if (tid < 4 * WINc) {
        const int w = tid % WINc;
        const int part = tid / WINc;
        const int d0 = part * 64;
        float a = 0.f;
        #pragma unroll 8
        for (int d = d0; d < d0 + 64; ++d)
            a = fmaf(sbarAcc[d], bf2f(winb[d * RS + w]), a);
        upart[part * WINc + w] = a;
    }
    __syncthreads();

    // ---- P5: ucomb_a ; sbar_b ----
    if (tid < WINc)
        ubuf[tid] = upart[tid] + upart[WINc + tid] +
                    upart[2 * WINc + tid] + upart[3 * WINc + tid];
    if (tid < Cc) {
        float v = 0.f;
        #pragma unroll
        for (int w8 = 0; w8 < 8; ++w8) v += colpart[w8 * Cc + tid];
        sbarAcc[tid] = v;
    }
    __syncthreads();

    // ---- P6: out_a ; u_b ----
    {
        const int co = tid & 255;
        const int part = tid >> 8;
        const int w0 = part * 40;
        float a = 0.f;
        #pragma unroll 8
        for (int w = w0; w < w0 + 40; ++w)
            a = fmaf(ubuf[w], WvWf[w * 256 + co], a);
        outpart[part * 256 + co] = a;
    }
    if (tid < 4 * WINc) {
        const int w = tid % WINc;
        const int part = tid / WINc;
        const int d0 = part * 64;
        float a = 0.f;
        #pragma unroll 8
        for (int d = d0; d < d0 + 64; ++d)
            a = fmaf(sbarAcc[d], bf2f(winb[d * RS + w + dB]), a);
        upart[part * WINc + w] = a;
    }
    __syncthreads();

    // ---- P7: final_a store ; ucomb_b ----
    if (tid < Cc)
        out[tid * Lc + lA] = outpart[tid] + outpart[Cc + tid] + bias3[tid];
    if (tid < WINc)
        ubuf[tid] = upart[tid] + upart[WINc + tid] +
                    upart[2 * WINc + tid] + upart[3 * WINc + tid];
    __syncthreads();

    // ---- P8: out_b ----
    {
        const int co = tid & 255;
        const int part = tid >> 8;
        const int w0 = part * 40;
        float a = 0.f;
        #pragma unroll 8
        for (int w = w0; w < w0 + 40; ++w)
            a = fmaf(ubuf[w], WvWf[w * 256 + co], a);
        outpart[part * 256 + co] = a;
    }
    __syncthreads();

    // ---- P9: final_b store ----
    if (tid < Cc)
        out[tid * Lc + lB] = outpart[tid] + outpart[Cc + tid] + bias3[tid];
}

// ---------------------------------------------------------------------------
extern "C" void kernel_launch(void* const* d_in, const int* in_sizes, int n_in,
                              void* d_out, int out_size, void* d_ws, size_t ws_size,
                              hipStream_t stream)
{
    const float* x  = (const float*)d_in[0];
    const float* Wq = (const float*)d_in[1];
    const float* bq = (const float*)d_in[2];
    const float* Wk = (const float*)d_in[3];
    // d_in[4] = bk — unused (row-constant in softmax)
    const float* Wv = (const float*)d_in[5];
    const float* bv = (const float*)d_in[6];
    const float* Wf = (const float*)d_in[7];
    const float* bf = (const float*)d_in[8];
    float* out = (float*)d_out;

    unsigned short* Gt = (unsigned short*)d_ws;                 // 2*96*96 u16 = 36864 B
    float* WvWf  = (float*)((char*)d_ws + 2 * SLOTS * GSTRIDE * 2);
    float* bias3 = WvWf + WINc * 256;                           // after 80*256 f32

    hipLaunchKernelGGL(precompute_kernel, dim3(2 * SLOTS + WINc + 1), dim3(256), 0, stream,
                       Wq, bq, Wk, Wv, bv, Wf, bf, Gt, WvWf, bias3);
    hipLaunchKernelGGL(local_attn_kernel, dim3(Lc / 2), dim3(512), 0, stream,
                       x, Gt, WvWf, bias3, out);
}

// Round 6
// 83.494 us; speedup vs baseline: 1.0169x; 1.0169x over previous
//
#include <hip/hip_runtime.h>

#define Lc    1024
#define Cc    256
#define WINc  80
#define SLOTS 96     // step-1 M dimension (3 tiles of 32)
#define RS    88     // LDS row stride in bf16 elems (176 B): 12-bank row shift -> ~4-way max
#define L2E   1.44269504088896340736f

typedef __attribute__((ext_vector_type(8)))  short bf16x8;
typedef __attribute__((ext_vector_type(16))) float f32x16;
typedef __attribute__((ext_vector_type(4)))  unsigned int u32x4;

__device__ inline float bf2f(unsigned short h) { return __uint_as_float(((unsigned int)h) << 16); }
__device__ inline unsigned int cvt_pk_bf16(float lo, float hi) {
    unsigned int r;
    asm("v_cvt_pk_bf16_f32 %0, %1, %2" : "=v"(r) : "v"(lo), "v"(hi));
    return r;
}
__device__ inline unsigned short f2bf(float f) {
    unsigned int u = __float_as_uint(f);
    unsigned int r = u + 0x7FFFu + ((u >> 16) & 1u);
    return (unsigned short)(r >> 16);
}

// ---------------------------------------------------------------------------
// Precompute into d_ws (all scaled by log2e where noted):
//  Gt[s][i] (96 x 88 bf16, stride 88): physical slot s holds logical col
//  j = swap23(s) of the augmented Gram operator:
//    j < 80 : G[i][j] = sum_f Wq[i,f]*Wk[j,f]          (* L2E)
//    j == 81: b2[i]   = sum_f bq[f]*Wk[i,f]            (* L2E)  -> beta slot
//    else 0.  swap23 (bits 2<->3) makes step1's 32x32 MFMA C-layout coincide
//  bit-exactly with step2's A-fragment layout (register handoff, no LDS).
//  WvWf[w][co] = (1/256)*sum_f Wv[w,f]*Wf[f,co];  bias3 = bv@Wf + bf.
//  bk is provably unused (row-constant in the softmax).
// ---------------------------------------------------------------------------
__global__ __launch_bounds__(128) void precompute_kernel(
    const float* __restrict__ Wq, const float* __restrict__ bq,
    const float* __restrict__ Wk, const float* __restrict__ Wv,
    const float* __restrict__ bv, const float* __restrict__ Wf,
    const float* __restrict__ bf,
    unsigned short* __restrict__ Gt, float* __restrict__ WvWf,
    float* __restrict__ bias3)
{
    const int b = blockIdx.x;
    if (b < SLOTS) {
        const int i = threadIdx.x;           // 0..87 used
        if (i >= RS) return;
        const int s = b;
        const int j = (s & ~12) | ((s & 4) << 1) | ((s & 8) >> 1);  // swap bits 2,3
        float acc = 0.f;
        bool nz = false;
        if (i < WINc) {
            if (j < WINc) {
                nz = true;
                for (int f = 0; f < 256; ++f)
                    acc = fmaf(Wq[i * 256 + f], Wk[j * 256 + f], acc);
            } else if (j == 81) {
                nz = true;
                for (int f = 0; f < 256; ++f)
                    acc = fmaf(bq[f], Wk[i * 256 + f], acc);
            }
        }
        Gt[s * RS + i] = nz ? f2bf(acc * L2E) : (unsigned short)0;
    } else if (b < SLOTS + 2 * WINc) {
        const int w = (b - SLOTS) >> 1;
        const int t = threadIdx.x + 128 * ((b - SLOTS) & 1);
        float acc = 0.f;
        for (int f = 0; f < 256; ++f)
            acc = fmaf(Wv[w * 256 + f], Wf[f * 256 + t], acc);
        WvWf[w * 256 + t] = acc * (1.0f / 256.0f);
    } else {
        const int t = threadIdx.x + 128 * (b - SLOTS - 2 * WINc);
        float acc = bf[t];
        for (int f = 0; f < 256; ++f)
            acc = fmaf(bv[f], Wf[f * 256 + t], acc);
        bias3[t] = acc;
    }
}

// ---------------------------------------------------------------------------
// Main kernel: one block (512 thr = 8 waves) per position l; wave owns 32 rows.
//  step1 (32x32x16): tt = Gt' @ win^T  (M=96, K=80) -> beta + step2 A-frags
//  step2 (32x32x16): S = T @ win^T     (256x256, K=80)
//  softmax (no max-subtract, log2e prebaked) -> ds_add_f32 column sums
//  u = colAcc @ win (atomic) ; out = u @ WvWf + bias3 (atomic) ; store
//  LDS total 65,344 B  (<= 64 KiB, targeting 2 blocks/CU residency)
// ---------------------------------------------------------------------------
__global__ __launch_bounds__(512, 2) void local_attn_kernel(
    const float* __restrict__ x,
    const unsigned short* __restrict__ Gt_ws,
    const float* __restrict__ WvWf, const float* __restrict__ bias3,
    float* __restrict__ out)
{
    __shared__ __align__(16) unsigned short winb[Cc * RS];    // 45056 B
    __shared__ __align__(16) unsigned short Gtb[SLOTS * RS];  // 16896 B
    __shared__ float sbeta[Cc];                                // 1024 B
    __shared__ float colAcc[Cc];                               // 1024 B
    __shared__ float outAcc[Cc];                               // 1024 B
    __shared__ float ubuf[WINc];                               // 320 B

    const int l = blockIdx.x;
    int s0 = l - WINc / 2;
    s0 = s0 < 0 ? 0 : (s0 > (Lc - WINc) ? (Lc - WINc) : s0);
    const int tid  = threadIdx.x;
    const int lane = tid & 63;
    const int wid  = tid >> 6;     // 0..7
    const int ln31 = lane & 31;
    const int hh   = lane >> 5;    // 0/1

    // ---- P0: stage window + Gt, init accumulators ----
    for (int i = tid; i < Cc * WINc / 8; i += 512) {
        const int c  = i & 255;
        const int ch = i >> 8;     // 0..9
        const float* xp = &x[c * Lc + s0 + ch * 8];
        union { u32x4 u; bf16x8 v; } pk;
        pk.u.x = cvt_pk_bf16(xp[0], xp[1]);
        pk.u.y = cvt_pk_bf16(xp[2], xp[3]);
        pk.u.z = cvt_pk_bf16(xp[4], xp[5]);
        pk.u.w = cvt_pk_bf16(xp[6], xp[7]);
        *(u32x4*)&winb[c * RS + ch * 8] = pk.u;
    }
    for (int i = tid; i < SLOTS * RS / 8; i += 512)            // 1056 x u32x4
        ((u32x4*)Gtb)[i] = ((const u32x4*)Gt_ws)[i];
    if (tid < Cc) { colAcc[tid] = 0.f; outAcc[tid] = bias3[tid]; }
    else if (tid < Cc + WINc) ubuf[tid - Cc] = 0.f;
    __syncthreads();

    // ---- P1: step1 + register A-frag handoff + step2 ----
    bf16x8 bwin[5];
    #pragma unroll
    for (int t = 0; t < 5; ++t)
        bwin[t] = *(const bf16x8*)&winb[(wid * 32 + ln31) * RS + t * 16 + hh * 8];

    f32x16 tt[3];
    #pragma unroll
    for (int mt = 0; mt < 3; ++mt) {
        f32x16 a;
        #pragma unroll
        for (int r = 0; r < 16; ++r) a[r] = 0.f;
        #pragma unroll
        for (int t = 0; t < 5; ++t) {
            bf16x8 g = *(const bf16x8*)&Gtb[(mt * 32 + ln31) * RS + t * 16 + hh * 8];
            a = __builtin_amdgcn_mfma_f32_32x32x16_bf16(g, bwin[t], a, 0, 0, 0);
        }
        tt[mt] = a;
    }
    // logical slot 81 (physical 81 = tt[2][9] on hh==0 lanes) is beta
    if (hh == 0) sbeta[wid * 32 + ln31] = tt[2][9];

    bf16x8 af[5];
    #pragma unroll
    for (int t = 0; t < 5; ++t) {
        const int m = t >> 1, o = 8 * (t & 1);
        union { u32x4 u; bf16x8 v; } pk;
        pk.u.x = cvt_pk_bf16(tt[m][o + 0], tt[m][o + 1]);
        pk.u.y = cvt_pk_bf16(tt[m][o + 2], tt[m][o + 3]);
        pk.u.z = cvt_pk_bf16(tt[m][o + 4], tt[m][o + 5]);
        pk.u.w = cvt_pk_bf16(tt[m][o + 6], tt[m][o + 7]);
        af[t] = pk.v;
    }

    f32x16 acc[8];
    #pragma unroll
    for (int nt = 0; nt < 8; ++nt) {
        f32x16 a;
        #pragma unroll
        for (int r = 0; r < 16; ++r) a[r] = 0.f;
        #pragma unroll
        for (int t = 0; t < 5; ++t) {
            bf16x8 b = *(const bf16x8*)&winb[(nt * 32 + ln31) * RS + t * 16 + hh * 8];
            a = __builtin_amdgcn_mfma_f32_32x32x16_bf16(af[t], b, a, 0, 0, 0);
        }
        acc[nt] = a;
    }
    __syncthreads();   // sbeta visible to all waves

    // ---- P2: softmax + atomic column sums ----
    {
        float zp[16];
        #pragma unroll
        for (int r = 0; r < 16; ++r) zp[r] = 0.f;
        #pragma unroll
        for (int nt = 0; nt < 8; ++nt) {
            const float sb = sbeta[nt * 32 + ln31];
            #pragma unroll
            for (int r = 0; r < 16; ++r) {
                const float e = exp2f(acc[nt][r] + sb);
                acc[nt][r] = e;
                zp[r] += e;
            }
        }
        #pragma unroll
        for (int r = 0; r < 16; ++r) {
            float z = zp[r];
            z += __shfl_xor(z, 1);
            z += __shfl_xor(z, 2);
            z += __shfl_xor(z, 4);
            z += __shfl_xor(z, 8);
            z += __shfl_xor(z, 16);
            zp[r] = __builtin_amdgcn_rcpf(z);
        }
        #pragma unroll
        for (int nt = 0; nt < 8; ++nt) {
            float v = 0.f;
            #pragma unroll
            for (int r = 0; r < 16; ++r) v = fmaf(acc[nt][r], zp[r], v);
            v += __shfl_xor(v, 32);
            if (lane < 32) atomicAdd(&colAcc[nt * 32 + ln31], v);
        }
    }
    __syncthreads();

    // ---- P3: u[w] = sum_d colAcc[d] * win[d][w]  (4-way d split, atomic) ----
    if (tid < 4 * WINc) {
        const int w = tid % WINc;
        const int d0 = (tid / WINc) * 64;
        float a = 0.f;
        #pragma unroll 8
        for (int d = d0; d < d0 + 64; ++d)
            a = fmaf(colAcc[d], bf2f(winb[d * RS + w]), a);
        atomicAdd(&ubuf[w], a);
    }
    __syncthreads();

    // ---- P4: out[co] = u @ WvWf  (2-way w split, atomic into bias3-seeded) ----
    {
        const int co = tid & 255;
        const int w0 = (tid >> 8) * 40;
        float a = 0.f;
        #pragma unroll 8
        for (int w = w0; w < w0 + 40; ++w)
            a = fmaf(ubuf[w], WvWf[w * 256 + co], a);
        atomicAdd(&outAcc[co], a);
    }
    __syncthreads();

    // ---- P5: store ----
    if (tid < Cc)
        out[tid * Lc + l] = outAcc[tid];
}

// ---------------------------------------------------------------------------
extern "C" void kernel_launch(void* const* d_in, const int* in_sizes, int n_in,
                              void* d_out, int out_size, void* d_ws, size_t ws_size,
                              hipStream_t stream)
{
    const float* x  = (const float*)d_in[0];
    const float* Wq = (const float*)d_in[1];
    const float* bq = (const float*)d_in[2];
    const float* Wk = (const float*)d_in[3];
    // d_in[4] = bk — unused (row-constant in softmax)
    const float* Wv = (const float*)d_in[5];
    const float* bv = (const float*)d_in[6];
    const float* Wf = (const float*)d_in[7];
    const float* bf = (const float*)d_in[8];
    float* out = (float*)d_out;

    unsigned short* Gt = (unsigned short*)d_ws;               // 96*88 u16 = 16896 B
    float* WvWf  = (float*)((char*)d_ws + SLOTS * RS * 2);    // 80*256 f32
    float* bias3 = WvWf + WINc * 256;                         // 256 f32

    hipLaunchKernelGGL(precompute_kernel, dim3(SLOTS + 2 * WINc + 2), dim3(128), 0, stream,
                       Wq, bq, Wk, Wv, bv, Wf, bf, Gt, WvWf, bias3);
    hipLaunchKernelGGL(local_attn_kernel, dim3(Lc), dim3(512), 0, stream,
                       x, Gt, WvWf, bias3, out);
}